// Round 6
// baseline (8239.615 us; speedup 1.0000x reference)
//
#include <hip/hip_runtime.h>
#include <float.h>

// FPS: N=524288 pts, M=2048 selected (idx[0]=0), out = pos[idxs] (2048x3 f32).
// 256 cooperative blocks x 128 threads = 512 waves on all 256 CUs.
// Block structure is irrelevant: NO LDS, NO __syncthreads in the loop.
// Per iteration, each wave:
//   butterfly-reduces its 1024 points -> lane0 publishes tagged u64 to the
//   wave's OWN 64B line (512 padded slots; R3's regression was dense packing,
//   8 publishers/line, not publisher count) -> polls all 512 slots
//   (8 coalesced loads/lane, in flight together) -> per-lane reduce +
//   butterfly + prefetched-coords ballot broadcast. One LLC hop/iteration.

#define NPTS     524288
#define MOUT     2048
#define NBLK     256
#define NTHR     128
#define NWAVE    (NTHR / 64)            // 2
#define GTHREADS (NBLK * NTHR)          // 32768
#define PPT      (NPTS / GTHREADS)      // 16
#define NSLOT    (NBLK * NWAVE)         // 512 publishers (one per wave)
#define SLOT_STRIDE 8                   // u64 stride -> own 64 B line
#define KPL      (NSLOT / 64)           // 8 slots polled per lane
#define MASK51   ((1ull << 51) - 1)

// slot word: [tag:13][fbits:32][idx_inv:19]
// fbits = IEEE bits of min_d (>=0 so bit order == value order)
// idx_inv = (NPTS-1)-idx: equal values -> smaller idx wins the max
// => first-occurrence tie-break == jnp.argmax (absmax 0.0 in R1-R5).
// Wave bests are globally unique (point ownership partitioned) => the winner
// lane after a reduce is identified by word equality (exactly one match).

__global__ void __launch_bounds__(NTHR, 1) fps_kernel(
    const float* __restrict__ pos, float* __restrict__ out,
    unsigned long long* __restrict__ slots)
{
    const unsigned tid  = threadIdx.x;
    const unsigned lane = tid & 63u;
    const unsigned wav  = tid >> 6;
    const unsigned blk  = blockIdx.x;
    const unsigned wid  = blk * NWAVE + wav;      // global wave id, 0..511
    const unsigned g    = blk * NTHR + tid;

    float X[PPT], Y[PPT], Z[PPT], D[PPT];
#pragma unroll
    for (int p = 0; p < PPT; ++p) {
        const unsigned idx = g + (unsigned)p * GTHREADS;
        X[p] = pos[3u * idx + 0];
        Y[p] = pos[3u * idx + 1];
        Z[p] = pos[3u * idx + 2];
        D[p] = FLT_MAX;
    }

    float px = pos[0], py = pos[1], pz = pos[2];
    if (g == 0) { out[0] = px; out[1] = py; out[2] = pz; }

    for (int i = 1; i < MOUT; ++i) {
        const unsigned p2 = (unsigned)i & 1u;
        // ---- distance update + per-thread argmax (exact fp32: no FMA,
        // ---- sum order (dx^2+dy^2)+dz^2; absmax==0 verified R1-R5) ----
        float bv = -1.0f;
        unsigned bi = 0;
#pragma unroll
        for (int p = 0; p < PPT; ++p) {
            float dx = __fsub_rn(X[p], px);
            float dy = __fsub_rn(Y[p], py);
            float dz = __fsub_rn(Z[p], pz);
            float d  = __fadd_rn(__fadd_rn(__fmul_rn(dx, dx), __fmul_rn(dy, dy)),
                                 __fmul_rn(dz, dz));
            float m  = fminf(D[p], d);
            D[p] = m;
            if (m > bv) { bv = m; bi = g + (unsigned)p * GTHREADS; }
        }
        unsigned long long best =
            ((unsigned long long)__float_as_uint(bv) << 19) |
            (unsigned long long)((NPTS - 1u) - bi);

        // ---- wave butterfly: all lanes get wave best ----
#pragma unroll
        for (int off = 32; off > 0; off >>= 1) {
            unsigned long long o = __shfl_xor(best, off, 64);
            if (o > best) best = o;
        }

        // ---- publish this wave's best to its own 64B line ----
        const unsigned long long tag = (unsigned long long)i;
        unsigned long long* buf = slots + p2 * (NSLOT * SLOT_STRIDE);
        if (lane == 0)
            __hip_atomic_store(&buf[wid * SLOT_STRIDE], (tag << 51) | best,
                               __ATOMIC_RELAXED, __HIP_MEMORY_SCOPE_AGENT);

        // ---- poll all 512 slots: lane reads slot lane+64k, k=0..7
        // ---- (coalesced 64-line bursts, all 8 in flight together) ----
        unsigned long long v[KPL];
        for (;;) {
            bool ok = true;
#pragma unroll
            for (int k = 0; k < KPL; ++k)
                v[k] = __hip_atomic_load(&buf[(lane + (unsigned)k * 64u) * SLOT_STRIDE],
                                         __ATOMIC_RELAXED, __HIP_MEMORY_SCOPE_AGENT);
#pragma unroll
            for (int k = 0; k < KPL; ++k) ok &= ((v[k] >> 51) == tag);
            if (__all(ok)) break;
            __builtin_amdgcn_s_sleep(1);
        }

        // ---- per-lane reduce of its 8 candidates ----
        unsigned long long c = v[0] & MASK51;
#pragma unroll
        for (int k = 1; k < KPL; ++k) {
            unsigned long long w = v[k] & MASK51;
            if (w > c) c = w;
        }
        // prefetch this lane's candidate coords; loads fly during butterfly
        unsigned cidx = (NPTS - 1u) - (unsigned)(c & 0x7FFFFull);
        float cx = pos[3u * cidx + 0];
        float cy = pos[3u * cidx + 1];
        float cz = pos[3u * cidx + 2];

        unsigned long long win = c;
#pragma unroll
        for (int off = 32; off > 0; off >>= 1) {
            unsigned long long o = __shfl_xor(win, off, 64);
            if (o > win) win = o;
        }
        unsigned long long bal = __ballot(win == c);   // exactly one lane matches
        int src = __ffsll(bal) - 1;
        px = __shfl(cx, src, 64);
        py = __shfl(cy, src, 64);
        pz = __shfl(cz, src, 64);

        if (g == 0) {
            out[3 * i + 0] = px; out[3 * i + 1] = py; out[3 * i + 2] = pz;
        }
    }
}

extern "C" void kernel_launch(void* const* d_in, const int* in_sizes, int n_in,
                              void* d_out, int out_size, void* d_ws, size_t ws_size,
                              hipStream_t stream) {
    const float* pos = (const float*)d_in[0];
    float* out = (float*)d_out;
    unsigned long long* slots = (unsigned long long*)d_ws;  // 2 x 512 x 64B = 64 KB
    // No memset: d_ws re-poisoned 0xAA each launch; poison decodes to tag
    // 0x1555, never a real tag (1..2047). Monotone tags + parity kill ABA.

    void* args[] = { (void*)&pos, (void*)&out, (void*)&slots };
    hipLaunchCooperativeKernel((void*)fps_kernel, dim3(NBLK), dim3(NTHR),
                               args, 0, stream);
}